// Round 2
// baseline (71.500 us; speedup 1.0000x reference)
//
#include <hip/hip_runtime.h>

// GaussianAdapter: out[b,r,f] = sum_t(w*v) / sum_t(w),
//   w = exp(-alpha*(r - ts)^2) * (ts>0) + EPS
// B=16, T=512, R=128, F=32.  Compute-bound: 33.5M exp ops; I/O ~2.5 MB.
// Single fused kernel. EPS factored out of the hot loop:
//   num = sum(e*v) + EPS*sum(v),  den = sum(e) + T*EPS
// Mask folded into a sentinel at staging time (ts<=0 -> 2e19 -> e = exp2(-inf) = 0).

constexpr int B_ = 16, T_ = 512, R_ = 128, F_ = 32;
constexpr int RB_ = 4;            // r-values per block (LDS tile reuse)
constexpr int TC_ = 128;          // t-rows per LDS chunk (32 KB)
constexpr int NC_ = T_ / TC_;     // 4 chunks
constexpr float EPS_ = 1e-7f;
constexpr float LOG2E_ = 1.4426950408889634f;

// Block: 256 threads. f = tid&31, rl = (tid>>5)&3, th = tid>>7 (T-half).
// Grid: B * R/RB = 512 blocks -> 2 blocks/CU, 2 waves/SIMD.
__global__ __launch_bounds__(256, 2) void ga_fused(
    const float* __restrict__ ts_g, const float* __restrict__ v_g,
    const float* __restrict__ ref_g, const float* __restrict__ alpha_g,
    float* __restrict__ out)
{
    __shared__ float2 tile[TC_ * F_];   // (ts, v) interleaved, [t][f] -> 32 KB
    __shared__ float4 red[RB_ * F_];    // cross-half reduction, 2 KB

    const int tid = threadIdx.x;
    const int f   = tid & 31;
    const int rl  = (tid >> 5) & (RB_ - 1);
    const int th  = tid >> 7;           // 0 or 1: which half of each t-chunk
    const int rb  = blockIdx.x % (R_ / RB_);
    const int b   = blockIdx.x / (R_ / RB_);
    const int r_idx = rb * RB_ + rl;

    const float r = ref_g[b * R_ + r_idx];
    const float c = -alpha_g[0] * LOG2E_;   // fold log2(e) into alpha: use exp2

    const float4* tsg4 = (const float4*)(ts_g + (size_t)b * T_ * F_);
    const float4* vg4  = (const float4*)(v_g  + (size_t)b * T_ * F_);

    float num = 0.f, den = 0.f, sv = 0.f;

    for (int ch = 0; ch < NC_; ++ch) {
        if (ch) __syncthreads();        // prev chunk's compute done before overwrite
        // ---- stage chunk: 1024 float4s each of ts/v; 4 per thread ----
        const int base4 = ch * (TC_ * F_ / 4);
        #pragma unroll
        for (int i = tid; i < TC_ * F_ / 4; i += 256) {
            float4 a = tsg4[base4 + i];
            float4 w = vg4[base4 + i];
            // fold mask: sentinel 2e19 -> c*d*d = -inf -> exp2 = 0 exactly
            a.x = (a.x > 0.f) ? a.x : 2e19f;
            a.y = (a.y > 0.f) ? a.y : 2e19f;
            a.z = (a.z > 0.f) ? a.z : 2e19f;
            a.w = (a.w > 0.f) ? a.w : 2e19f;
            float4* dst = (float4*)tile + 2 * i;
            dst[0] = make_float4(a.x, w.x, a.y, w.y);
            dst[1] = make_float4(a.z, w.z, a.w, w.w);
        }
        __syncthreads();

        // ---- hot loop: 64 t per thread; ds_read_b64 + 6 VALU + v_exp ----
        const float2* tp = tile + th * (TC_ / 2) * F_ + f;
        #pragma unroll 16
        for (int t = 0; t < TC_ / 2; ++t) {
            float2 a = tp[t * F_];               // 2-way lane alias: free
            float d = r - a.x;
            float e = __builtin_amdgcn_exp2f(c * d * d);
            num = fmaf(e, a.y, num);
            den += e;
            sv  += a.y;                          // EPS term, factored
        }
    }

    // ---- reduce across the two T-halves ----
    __syncthreads();
    if (th == 1) red[rl * F_ + f] = make_float4(num, den, sv, 0.f);
    __syncthreads();
    if (th == 0) {
        float4 o = red[rl * F_ + f];
        float n = (num + o.x) + EPS_ * (sv + o.z);
        float d = (den + o.y) + (float)T_ * EPS_;
        out[(b * R_ + r_idx) * F_ + f] = n / d;
    }
}

extern "C" void kernel_launch(void* const* d_in, const int* in_sizes, int n_in,
                              void* d_out, int out_size, void* d_ws, size_t ws_size,
                              hipStream_t stream) {
    const float* timesteps = (const float*)d_in[0];   // (B,T,F)
    const float* values    = (const float*)d_in[1];   // (B,T,F)
    const float* ref_ts    = (const float*)d_in[2];   // (B,R)
    const float* alpha     = (const float*)d_in[3];   // (1,)
    float* out = (float*)d_out;                        // (B,R,F)

    ga_fused<<<B_ * (R_ / RB_), 256, 0, stream>>>(
        timesteps, values, ref_ts, alpha, out);
}

// Round 3
// 70.037 us; speedup vs baseline: 1.0209x; 1.0209x over previous
//
#include <hip/hip_runtime.h>

// GaussianAdapter: out[b,r,f] = sum_t(w*v) / sum_t(w),
//   w = exp(-alpha*(r - ts)^2) * (ts>0) + EPS
// B=16, T=512, R=128, F=32.  Compute-bound: 33.5M exp ops; I/O ~2.5 MB.
// EPS factored: num = sum(e*v) + EPS*sum(v), den = sum(e) + T*EPS.
// Mask folded into sentinel at staging (ts<=0 -> 2e19 -> exp2(-inf) = 0).
// This rev: 512-thr blocks (4 waves/SIMD for latency hiding) + packed-f32
// (v_pk_*) hot loop, t paired (j, j+16) for independent ds_read_b64s.

constexpr int B_ = 16, T_ = 512, R_ = 128, F_ = 32;
constexpr int RB_ = 4;            // r-values per block (LDS tile reuse)
constexpr int TC_ = 128;          // t-rows per LDS chunk (32 KB)
constexpr int NC_ = T_ / TC_;     // 4 chunks
constexpr float EPS_ = 1e-7f;
constexpr float LOG2E_ = 1.4426950408889634f;

typedef float v2f __attribute__((ext_vector_type(2)));

// Block: 512 threads. f = tid&31, rl = (tid>>5)&3, th = tid>>7 in {0..3}.
// Grid: B * R/RB = 512 blocks -> 2 blocks/CU = 16 waves/CU = 4 waves/SIMD.
__global__ __launch_bounds__(512, 4) void ga_fused(
    const float* __restrict__ ts_g, const float* __restrict__ v_g,
    const float* __restrict__ ref_g, const float* __restrict__ alpha_g,
    float* __restrict__ out)
{
    __shared__ float2 tile[TC_ * F_];       // (ts, v) interleaved -> 32 KB
    __shared__ float4 red[3][RB_ * F_];     // cross-th partials, 6 KB

    const int tid = threadIdx.x;
    const int f   = tid & 31;
    const int rl  = (tid >> 5) & (RB_ - 1);
    const int th  = tid >> 7;               // quarter of each t-chunk
    const int rb  = blockIdx.x % (R_ / RB_);
    const int b   = blockIdx.x / (R_ / RB_);
    const int r_idx = rb * RB_ + rl;

    const float r = ref_g[b * R_ + r_idx];
    const float c = -alpha_g[0] * LOG2E_;   // exp(x) = exp2(x*log2e), folded
    const v2f rr = {r, r};
    const v2f cc = {c, c};

    const float4* tsg4 = (const float4*)(ts_g + (size_t)b * T_ * F_);
    const float4* vg4  = (const float4*)(v_g  + (size_t)b * T_ * F_);

    v2f num = {0.f, 0.f}, den = {0.f, 0.f}, sv = {0.f, 0.f};

    for (int ch = 0; ch < NC_; ++ch) {
        if (ch) __syncthreads();
        // ---- stage chunk: 1024 float4 each of ts/v; 2 per thread ----
        const int base4 = ch * (TC_ * F_ / 4);
        #pragma unroll
        for (int i = tid; i < TC_ * F_ / 4; i += 512) {
            float4 a = tsg4[base4 + i];
            float4 w = vg4[base4 + i];
            a.x = (a.x > 0.f) ? a.x : 2e19f;   // sentinel: c*d*d -> -inf
            a.y = (a.y > 0.f) ? a.y : 2e19f;
            a.z = (a.z > 0.f) ? a.z : 2e19f;
            a.w = (a.w > 0.f) ? a.w : 2e19f;
            float4* dst = (float4*)tile + 2 * i;
            dst[0] = make_float4(a.x, w.x, a.y, w.y);
            dst[1] = make_float4(a.z, w.z, a.w, w.w);
        }
        __syncthreads();

        // ---- hot loop: th owns rows [th*32, th*32+32); pairs (j, j+16) ----
        const float2* tp = tile + (th * 32) * F_ + f;
        #pragma unroll 8
        for (int j = 0; j < 16; ++j) {
            float2 a0 = tp[j * F_];            // independent ds_read_b64 x2
            float2 a1 = tp[(j + 16) * F_];
            v2f ts2 = {a0.x, a1.x};
            v2f vv  = {a0.y, a1.y};
            v2f d = rr - ts2;                  // v_pk_add (neg)
            v2f p = (cc * d) * d;              // v_pk_mul x2
            v2f e;
            e.x = __builtin_amdgcn_exp2f(p.x); // trans pipe, scalar only
            e.y = __builtin_amdgcn_exp2f(p.y);
            num += e * vv;                     // v_pk_fma
            den += e;                          // v_pk_add
            sv  += vv;                         // v_pk_add (EPS term, factored)
        }
    }

    // ---- reduce the 4 T-quarters ----
    float fn = num.x + num.y, fd = den.x + den.y, fs = sv.x + sv.y;
    if (th) red[th - 1][rl * F_ + f] = make_float4(fn, fd, fs, 0.f);
    __syncthreads();
    if (th == 0) {
        #pragma unroll
        for (int k = 0; k < 3; ++k) {
            float4 o = red[k][rl * F_ + f];
            fn += o.x; fd += o.y; fs += o.z;
        }
        float n = fn + EPS_ * fs;
        float d = fd + (float)T_ * EPS_;
        out[(b * R_ + r_idx) * F_ + f] = n / d;
    }
}

extern "C" void kernel_launch(void* const* d_in, const int* in_sizes, int n_in,
                              void* d_out, int out_size, void* d_ws, size_t ws_size,
                              hipStream_t stream) {
    const float* timesteps = (const float*)d_in[0];   // (B,T,F)
    const float* values    = (const float*)d_in[1];   // (B,T,F)
    const float* ref_ts    = (const float*)d_in[2];   // (B,R)
    const float* alpha     = (const float*)d_in[3];   // (1,)
    float* out = (float*)d_out;                        // (B,R,F)

    ga_fused<<<B_ * (R_ / RB_), 512, 0, stream>>>(
        timesteps, values, ref_ts, alpha, out);
}